// Round 5
// baseline (430.916 us; speedup 1.0000x reference)
//
#include <hip/hip_runtime.h>

#define HD 4096

typedef __attribute__((ext_vector_type(4))) float f32x4;
typedef __attribute__((ext_vector_type(8))) short bf16x8;
typedef __attribute__((ext_vector_type(4))) short s16x4;
typedef __attribute__((ext_vector_type(2))) unsigned u32x2;

__device__ __forceinline__ short f2bf(float f) {
    unsigned u = __float_as_uint(f);
    u += 0x7fffu + ((u >> 16) & 1u);   // RNE (finite inputs)
    return (short)(u >> 16);
}
__device__ __forceinline__ float bf2f(short s) {
    return __uint_as_float(((unsigned)(unsigned short)s) << 16);
}
__device__ __forceinline__ float sigmoidf_(float x) { return 1.f / (1.f + __expf(-x)); }

// ---------------------------------------------------------------------------
// fp32 activations -> bf16. X: 65536 f32x4, h0: 131072 f32x4. Grid 768x256.
// ---------------------------------------------------------------------------
__global__ void convert_kernel(const float* __restrict__ X, const float* __restrict__ h0,
                               short* __restrict__ Xbf, short* __restrict__ H0bf)
{
    const int i = blockIdx.x * blockDim.x + threadIdx.x;
    if (i < 65536) {
        f32x4 v = ((const f32x4*)X)[i];
        s16x4 o = { f2bf(v[0]), f2bf(v[1]), f2bf(v[2]), f2bf(v[3]) };
        ((s16x4*)Xbf)[i] = o;
    } else {
        const int j = i - 65536;
        f32x4 v = ((const f32x4*)h0)[j];
        s16x4 o = { f2bf(v[0]), f2bf(v[1]), f2bf(v[2]), f2bf(v[3]) };
        ((s16x4*)H0bf)[j] = o;
    }
}

// ---------------------------------------------------------------------------
// Panel GEMM, density-optimized. Block = 16 W-rows x 1024-k quarter.
// Stream phase: each wave reads 8 rows, 4KB CONTIGUOUS per row (f32x4/lane
// back-to-back), cvt to bf16, XOR-swizzled into 32KB LDS.
// Block IDs map monotonically to W addresses (khq minor, panel major) so the
// resident set of blocks covers a dense multi-MB sliding window of W.
// Compute: 2 waves split batch (32 rows each); 32 k-steps, A from L2 with a
// 4-deep register ring, B from LDS 2-ahead. Partials stored bf16 to P.
// ---------------------------------------------------------------------------
__global__ __launch_bounds__(128, 2) void panel_gemm_kernel(
    const short* __restrict__ A0, const short* __restrict__ A1,
    const float* __restrict__ W0, const float* __restrict__ W1,
    short* __restrict__ P, int Ntot, int npan)
{
    __shared__ short smem[16][1024];     // 32 KB: 16 rows x 1024 k bf16
    const int tid = threadIdx.x, lane = tid & 63, wv = tid >> 6;   // wv 0..1
    const int ar = lane & 15, kg = lane >> 4;
    const int bid = blockIdx.x;
    const int group = npan * 4;
    const int mat = bid / group;
    const int rem = bid - mat * group;
    const int p = rem >> 2, khq = rem & 3;
    const short* A = mat ? A1 : A0;
    const float* W = mat ? W1 : W0;
    const int kq = mat * 4 + khq;
    const int n0 = p * 16;

    // ---------------- stream phase ----------------
    const float* wb = W + (long)n0 * HD + khq * 1024 + (lane << 2);
    char* lds = (char*)&smem[0][0];
    f32x4 rr[2][4];

#define ISSUE_ROW(RQ, RR) do { \
    const float* rp_ = wb + (long)(wv * 8 + (RR)) * HD; \
    _Pragma("unroll") for (int j_ = 0; j_ < 4; ++j_) \
        rr[RQ][j_] = *(const f32x4*)(rp_ + j_ * 256); \
    __builtin_amdgcn_sched_barrier(0); \
} while (0)

    ISSUE_ROW(0, 0);
    ISSUE_ROW(1, 1);
    #pragma unroll
    for (int r = 0; r < 8; ++r) {
        const int R = wv * 8 + r;
        const int q = r & 1;
        char* rowb = lds + R * 2048 + ((lane & 1) << 3);
        #pragma unroll
        for (int j = 0; j < 4; ++j) {
            unsigned lo_, hi_;
            asm("v_cvt_pk_bf16_f32 %0, %1, %2" : "=v"(lo_) : "v"(rr[q][j][0]), "v"(rr[q][j][1]));
            asm("v_cvt_pk_bf16_f32 %0, %1, %2" : "=v"(hi_) : "v"(rr[q][j][2]), "v"(rr[q][j][3]));
            const int g = (j * 32 + (lane >> 1)) ^ (R & 7);
            u32x2 v_ = { lo_, hi_ };
            *(u32x2*)(rowb + g * 16) = v_;
        }
        if (r + 2 < 8) ISSUE_ROW(q, r + 2);
    }
    __syncthreads();

    // ---------------- compute phase ----------------
    // wave wv: batch rows [wv*32, wv*32+32) -> 2 m-frags; 16 n-cols = n0..n0+15
    const short* ab = A + (long)(wv * 32 + ar) * HD + khq * 1024 + kg * 8;
    const char* lb = lds + ar * 2048;
    const int swz = ar & 7;

    f32x4 acc0 = {0.f, 0.f, 0.f, 0.f}, acc1 = {0.f, 0.f, 0.f, 0.f};
    bf16x8 aR[4][2];
    bf16x8 bR[2];

    #pragma unroll
    for (int s = 0; s < 4; ++s) {
        aR[s][0] = *(const bf16x8*)(ab + s * 32);
        aR[s][1] = *(const bf16x8*)(ab + 65536 + s * 32);
    }
    bR[0] = *(const bf16x8*)(lb + (((kg) ^ swz) << 4));
    bR[1] = *(const bf16x8*)(lb + (((4 + kg) ^ swz) << 4));

    for (int su = 0; su < 8; ++su) {
        #pragma unroll
        for (int i = 0; i < 4; ++i) {
            const int s = su * 4 + i;
            acc0 = __builtin_amdgcn_mfma_f32_16x16x32_bf16(aR[i][0], bR[i & 1], acc0, 0, 0, 0);
            acc1 = __builtin_amdgcn_mfma_f32_16x16x32_bf16(aR[i][1], bR[i & 1], acc1, 0, 0, 0);
            if (su < 7) {
                aR[i][0] = *(const bf16x8*)(ab + (s + 4) * 32);
                aR[i][1] = *(const bf16x8*)(ab + 65536 + (s + 4) * 32);
            }
            if (su < 7 || i < 2) {
                bR[i & 1] = *(const bf16x8*)(lb + ((((s + 2) * 4 + kg) ^ swz) << 4));
            }
        }
    }

    // partial write (bf16): P[kq][batch][n]
    short* pr = P + ((long)kq * 64 + wv * 32) * Ntot + n0 + ar;
    #pragma unroll
    for (int r = 0; r < 4; ++r) {
        pr[(long)(kg * 4 + r) * Ntot]      = f2bf(acc0[r]);
        pr[(long)(16 + kg * 4 + r) * Ntot] = f2bf(acc1[r]);
    }
}

// ---------------------------------------------------------------------------
// Reduce nkq bf16 partials + biases + LSTM cell. 65536 threads.
// P layout: [nkq][64][16384] bf16, gates i,f,g,o at col g*4096 + hc.
// ---------------------------------------------------------------------------
__global__ void cell_kernel(const short* __restrict__ P, int nkq,
                            const float* __restrict__ bi, const float* __restrict__ bh,
                            const float* __restrict__ cprev,
                            float* __restrict__ hout, float* __restrict__ cout,
                            float* __restrict__ ms, short* __restrict__ hbf)
{
    const int idx = blockIdx.x * blockDim.x + threadIdx.x;  // 0..65535
    const int b = idx >> 10;
    const int hc = (idx & 1023) * 4;

    f32x4 g[4] = {{0,0,0,0},{0,0,0,0},{0,0,0,0},{0,0,0,0}};
    for (int kq = 0; kq < nkq; ++kq) {
        const short* pb = P + ((long)kq * 64 + b) * 16384 + hc;
        #pragma unroll
        for (int gt = 0; gt < 4; ++gt) {
            s16x4 v = *(const s16x4*)(pb + gt * 4096);
            #pragma unroll
            for (int e = 0; e < 4; ++e) g[gt][e] += bf2f(v[e]);
        }
    }
    #pragma unroll
    for (int gt = 0; gt < 4; ++gt) {
        g[gt] += *(const f32x4*)(bi + gt * HD + hc);
        g[gt] += *(const f32x4*)(bh + gt * HD + hc);
    }
    const long off = (long)b * HD + hc;
    f32x4 c = *(const f32x4*)(cprev + off);
    f32x4 hn, cn; s16x4 hb;
    #pragma unroll
    for (int e = 0; e < 4; ++e) {
        float cv = sigmoidf_(g[1][e]) * c[e] + sigmoidf_(g[0][e]) * tanhf(g[2][e]);
        float hv = sigmoidf_(g[3][e]) * tanhf(cv);
        cn[e] = cv; hn[e] = hv; hb[e] = f2bf(hv);
    }
    *(f32x4*)(hout + off) = hn;
    *(f32x4*)(cout + off) = cn;
    if (ms) *(f32x4*)(ms + off) = hn;
    *(s16x4*)(hbf + off) = hb;
}

// ---------------------------------------------------------------------------
// Head finish: hid[b][n] = relu(sum_kq P[kq][b][n] + bc1[n]). N=2048, bf16 P.
// ---------------------------------------------------------------------------
__global__ void headfin_kernel(const short* __restrict__ P, int nkq,
                               const float* __restrict__ bc1, float* __restrict__ hid)
{
    const int idx = blockIdx.x * blockDim.x + threadIdx.x;  // 0..32767
    const int b = idx >> 9;
    const int n = (idx & 511) * 4;
    f32x4 s = {0.f, 0.f, 0.f, 0.f};
    for (int kq = 0; kq < nkq; ++kq) {
        s16x4 v = *(const s16x4*)(P + ((long)kq * 64 + b) * 2048 + n);
        #pragma unroll
        for (int e = 0; e < 4; ++e) s[e] += bf2f(v[e]);
    }
    s += *(const f32x4*)(bc1 + n);
    #pragma unroll
    for (int e = 0; e < 4; ++e) s[e] = fmaxf(s[e], 0.f);
    *(f32x4*)(hid + (long)b * 2048 + n) = s;
}

// ---------------------------------------------------------------------------
// count = relu(hid @ Wc2^T + bc2). [64,2048] x [2048] -> [64].
// ---------------------------------------------------------------------------
__global__ void count_kernel(const float* __restrict__ hid, const float* __restrict__ Wc2,
                             const float* __restrict__ bc2, float* __restrict__ out)
{
    const int tid = threadIdx.x;
    const int b = tid >> 2, q = tid & 3;
    const float* hp = hid + (long)b * 2048 + q * 512;
    const float* wp = Wc2 + q * 512;
    float s = 0.f;
    #pragma unroll 4
    for (int k = 0; k < 512; k += 4) {
        f32x4 h4 = *(const f32x4*)(hp + k);
        f32x4 w4 = *(const f32x4*)(wp + k);
        s += h4[0] * w4[0] + h4[1] * w4[1] + h4[2] * w4[2] + h4[3] * w4[3];
    }
    s += __shfl_xor(s, 1);
    s += __shfl_xor(s, 2);
    if (q == 0) out[b] = fmaxf(s + bc2[0], 0.f);
}

// ---------------------------------------------------------------------------
extern "C" void kernel_launch(void* const* d_in, const int* in_sizes, int n_in,
                              void* d_out, int out_size, void* d_ws, size_t ws_size,
                              hipStream_t stream)
{
    const float* X    = (const float*)d_in[0];
    const float* h0   = (const float*)d_in[1];
    const float* c0   = (const float*)d_in[2];
    const float* Wih0 = (const float*)d_in[3];
    const float* Whh0 = (const float*)d_in[4];
    const float* bih0 = (const float*)d_in[5];
    const float* bhh0 = (const float*)d_in[6];
    const float* Wih1 = (const float*)d_in[7];
    const float* Whh1 = (const float*)d_in[8];
    const float* bih1 = (const float*)d_in[9];
    const float* bhh1 = (const float*)d_in[10];
    const float* Wc1  = (const float*)d_in[11];
    const float* bc1  = (const float*)d_in[12];
    const float* Wc2  = (const float*)d_in[13];
    const float* bc2  = (const float*)d_in[14];

    float* out  = (float*)d_out;
    float* ms   = out;                  // memory_state [64][4096]
    float* hnew = out + 262144;         // h_new [2][64][4096]
    float* cnew = out + 786432;         // c_new [2][64][4096]
    float* cnt  = out + 1310720;        // count [64]

    char* ws = (char*)d_ws;
    short* Xbf  = (short*)ws;                       // 512 KB
    short* H0bf = (short*)(ws + (1u << 19));        // 1 MB
    short* h1bf = (short*)(ws + 3u * (1u << 19));   // 512 KB
    short* h2bf = (short*)(ws + (1u << 21));        // 512 KB
    float* hid  = (float*)(ws + 5u * (1u << 19));   // 512 KB
    short* Pp   = (short*)(ws + 3u * (1u << 20));   // 16 MB bf16 partials [8][64][16384]

    hipLaunchKernelGGL(convert_kernel, dim3(768), dim3(256), 0, stream, X, h0, Xbf, H0bf);

    // layers: 2 mats x 1024 panels x 4 k-quarters = 8192 blocks, 128 thr
    hipLaunchKernelGGL(panel_gemm_kernel, dim3(8192), dim3(128), 0, stream,
                       Xbf, H0bf, Wih0, Whh0, Pp, 16384, 1024);
    hipLaunchKernelGGL(cell_kernel, dim3(256), dim3(256), 0, stream,
                       Pp, 8, bih0, bhh0, c0, hnew, cnew, (float*)nullptr, h1bf);

    hipLaunchKernelGGL(panel_gemm_kernel, dim3(8192), dim3(128), 0, stream,
                       h1bf, H0bf + 262144, Wih1, Whh1, Pp, 16384, 1024);
    hipLaunchKernelGGL(cell_kernel, dim3(256), dim3(256), 0, stream,
                       Pp, 8, bih1, bhh1, c0 + 262144, hnew + 262144, cnew + 262144, ms, h2bf);

    // head: 1 mat x 128 panels x 4 k-quarters = 512 blocks
    hipLaunchKernelGGL(panel_gemm_kernel, dim3(512), dim3(128), 0, stream,
                       h2bf, h2bf, Wc1, Wc1, Pp, 2048, 128);
    hipLaunchKernelGGL(headfin_kernel, dim3(128), dim3(256), 0, stream, Pp, 4, bc1, hid);
    hipLaunchKernelGGL(count_kernel, dim3(1), dim3(256), 0, stream, hid, Wc2, bc2, cnt);
}

// Round 6
// 379.599 us; speedup vs baseline: 1.1352x; 1.1352x over previous
//
#include <hip/hip_runtime.h>

#define HD 4096

typedef __attribute__((ext_vector_type(4))) float f32x4;
typedef __attribute__((ext_vector_type(8))) short bf16x8;
typedef __attribute__((ext_vector_type(4))) short s16x4;
typedef __attribute__((ext_vector_type(2))) unsigned u32x2;

__device__ __forceinline__ short f2bf(float f) {
    unsigned u = __float_as_uint(f);
    u += 0x7fffu + ((u >> 16) & 1u);   // RNE (finite inputs)
    return (short)(u >> 16);
}

// 8x fp32 -> 8x bf16 via v_cvt_pk_bf16_f32 (2 elems/instr, RNE)
__device__ __forceinline__ bf16x8 cvt8pk(f32x4 lo, f32x4 hi) {
    union { bf16x8 v; unsigned u[4]; } r;
    asm("v_cvt_pk_bf16_f32 %0, %1, %2" : "=v"(r.u[0]) : "v"(lo[0]), "v"(lo[1]));
    asm("v_cvt_pk_bf16_f32 %0, %1, %2" : "=v"(r.u[1]) : "v"(lo[2]), "v"(lo[3]));
    asm("v_cvt_pk_bf16_f32 %0, %1, %2" : "=v"(r.u[2]) : "v"(hi[0]), "v"(hi[1]));
    asm("v_cvt_pk_bf16_f32 %0, %1, %2" : "=v"(r.u[3]) : "v"(hi[2]), "v"(hi[3]));
    return r.v;
}

__device__ __forceinline__ void gl_lds16(const float* g, float* l) {
    typedef const __attribute__((address_space(1))) void* gas_t;
    typedef __attribute__((address_space(3))) void* las_t;
    __builtin_amdgcn_global_load_lds((gas_t)(const void*)g, (las_t)(void*)l, 16, 0, 0);
}

__device__ __forceinline__ float sigmoidf_(float x) { return 1.f / (1.f + __expf(-x)); }

// ---------------------------------------------------------------------------
// fp32 activations -> bf16. X: 65536 f32x4, h0: 131072 f32x4. Grid 768x256.
// ---------------------------------------------------------------------------
__global__ void convert_kernel(const float* __restrict__ X, const float* __restrict__ h0,
                               short* __restrict__ Xbf, short* __restrict__ H0bf)
{
    const int i = blockIdx.x * blockDim.x + threadIdx.x;
    if (i < 65536) {
        f32x4 v = ((const f32x4*)X)[i];
        s16x4 o = { f2bf(v[0]), f2bf(v[1]), f2bf(v[2]), f2bf(v[3]) };
        ((s16x4*)Xbf)[i] = o;
    } else {
        const int j = i - 65536;
        f32x4 v = ((const f32x4*)h0)[j];
        s16x4 o = { f2bf(v[0]), f2bf(v[1]), f2bf(v[2]), f2bf(v[3]) };
        ((s16x4*)H0bf)[j] = o;
    }
}

// ---------------------------------------------------------------------------
// Partial GEMM: P[kq][64][N] = A(bf16)[64][K-slice] @ W(fp32)^T.
// Round-2 structure (measured best: 186 us/layer, 2.89 TB/s effective):
// grid = (N/64) * nkq blocks x 256 thr; block = 64 cols x KB K-slice;
// wave wv: 16 cols, full block K-slice. K split across the two source
// matrices (A0/W0 then A1/W1).
// W staged via global_load_lds into wave-private LDS dbuf (no barriers),
// counted vmcnt(12); LDS granule-swizzled via the GLOBAL source (rule #21).
// ---------------------------------------------------------------------------
#define STAGE(LB, TT) \
    _Pragma("unroll") for (int i_ = 0; i_ < 4; ++i_) \
        gl_lds16(wsrc[i_] + (TT) * 64, (LB) + i_ * 256);

#define ALOAD(BUF, TT) \
    _Pragma("unroll") for (int m_ = 0; m_ < 4; ++m_) \
    _Pragma("unroll") for (int ks_ = 0; ks_ < 2; ++ks_) \
        a[BUF][m_][ks_] = *(const bf16x8*)(aBase + m_ * 16 * HD + (TT) * 64 + ks_ * 32);

#define COMP(LB, BUF) \
    _Pragma("unroll") for (int ks_ = 0; ks_ < 2; ++ks_) { \
        const int bofs_ = ar * 64 + ks_ * 32; \
        f32x4 wlo_ = *(const f32x4*)((LB) + bofs_ + ((((kg * 2)    ) ^ (ar & 7)) << 2)); \
        f32x4 whi_ = *(const f32x4*)((LB) + bofs_ + ((((kg * 2) + 1) ^ (ar & 7)) << 2)); \
        bf16x8 wb_ = cvt8pk(wlo_, whi_); \
        _Pragma("unroll") for (int m_ = 0; m_ < 4; ++m_) \
            acc[m_] = __builtin_amdgcn_mfma_f32_16x16x32_bf16(a[BUF][m_][ks_], wb_, acc[m_], 0, 0, 0); \
    }

__global__ __launch_bounds__(256, 4) void gemm_part_kernel(
    const short* __restrict__ A0, const short* __restrict__ A1,
    const float* __restrict__ W0, const float* __restrict__ W1,
    float* __restrict__ P, int N, int nkq, int KB)
{
    __shared__ float wlds[4][2][1024];   // [wave][buf][16 rows x 64 k] = 32 KB
    const int tid = threadIdx.x, lane = tid & 63, wv = tid >> 6;
    const int ar = lane & 15, kg = lane >> 4;
    const int bid = blockIdx.x;
    const int ntile = bid / nkq, kq = bid % nkq;
    const int half = nkq >> 1;
    const int kqh = (kq >= half) ? 1 : 0;
    const int kqi = kq - kqh * half;
    const short* A = kqh ? A1 : A0;
    const float* W = kqh ? W1 : W0;
    const int kbase = kqi * KB;          // float/short offset within the half
    const int T = KB >> 6;
    const int n0w = ntile * 64 + wv * 16;

    // A fragment base: row (m*16 + ar), k = kbase + kg*8
    const short* aBase = A + (long)ar * HD + kbase + kg * 8;

    // global_load_lds sources: instr i covers LDS rows i*4 + (lane>>4);
    // within-row 16B granule q = lane&15 holds logical granule q ^ (row&7).
    const float* wsrc[4];
    #pragma unroll
    for (int i = 0; i < 4; ++i) {
        const int row = i * 4 + kg;
        wsrc[i] = W + (long)(n0w + row) * HD + kbase + (((lane & 15) ^ (row & 7)) << 2);
    }
    float* lb0 = &wlds[wv][0][0];
    float* lb1 = &wlds[wv][1][0];

    const f32x4 zero = {0.f, 0.f, 0.f, 0.f};
    f32x4 acc[4] = {zero, zero, zero, zero};
    bf16x8 a[2][4][2];

    STAGE(lb0, 0); ALOAD(0, 0);
    const int T2 = T >> 1;
    for (int u = 0; u < T2; ++u) {
        const int t0 = u * 2, t1 = t0 + 1;
        STAGE(lb1, t1); ALOAD(1, t1);
        asm volatile("s_waitcnt vmcnt(12)" ::: "memory");
        __builtin_amdgcn_sched_barrier(0);
        COMP(lb0, 0);
        if (u + 1 < T2) {
            STAGE(lb0, t0 + 2); ALOAD(0, t0 + 2);
            asm volatile("s_waitcnt vmcnt(12)" ::: "memory");
        } else {
            asm volatile("s_waitcnt vmcnt(0)" ::: "memory");
        }
        __builtin_amdgcn_sched_barrier(0);
        COMP(lb1, 1);
    }

    // write partial: P[kq][brow][col], brow = m*16 + kg*4 + r, col = n0w + ar
    float* pr = P + (long)kq * 64 * N + n0w + ar;
    #pragma unroll
    for (int m = 0; m < 4; ++m)
        #pragma unroll
        for (int r = 0; r < 4; ++r)
            pr[(long)(m * 16 + kg * 4 + r) * N] = acc[m][r];
}

// ---------------------------------------------------------------------------
// Reduce nkq partials + biases + LSTM cell. 65536 threads, f32x4 per thread.
// P layout: [nkq][64][16384], gates i,f,g,o at col g*4096 + hc.
// ---------------------------------------------------------------------------
__global__ void cell_kernel(const float* __restrict__ P, int nkq,
                            const float* __restrict__ bi, const float* __restrict__ bh,
                            const float* __restrict__ cprev,
                            float* __restrict__ hout, float* __restrict__ cout,
                            float* __restrict__ ms, short* __restrict__ hbf)
{
    const int idx = blockIdx.x * blockDim.x + threadIdx.x;  // 0..65535
    const int b = idx >> 10;
    const int hc = (idx & 1023) * 4;

    f32x4 g[4] = {{0,0,0,0},{0,0,0,0},{0,0,0,0},{0,0,0,0}};
    for (int kq = 0; kq < nkq; ++kq) {
        const float* pb = P + ((long)kq * 64 + b) * 16384 + hc;
        #pragma unroll
        for (int gt = 0; gt < 4; ++gt)
            g[gt] += *(const f32x4*)(pb + gt * 4096);
    }
    #pragma unroll
    for (int gt = 0; gt < 4; ++gt) {
        g[gt] += *(const f32x4*)(bi + gt * HD + hc);
        g[gt] += *(const f32x4*)(bh + gt * HD + hc);
    }
    const long off = (long)b * HD + hc;
    f32x4 c = *(const f32x4*)(cprev + off);
    f32x4 hn, cn; s16x4 hb;
    #pragma unroll
    for (int e = 0; e < 4; ++e) {
        float cv = sigmoidf_(g[1][e]) * c[e] + sigmoidf_(g[0][e]) * tanhf(g[2][e]);
        float hv = sigmoidf_(g[3][e]) * tanhf(cv);
        cn[e] = cv; hn[e] = hv; hb[e] = f2bf(hv);
    }
    *(f32x4*)(hout + off) = hn;
    *(f32x4*)(cout + off) = cn;
    if (ms) *(f32x4*)(ms + off) = hn;
    *(s16x4*)(hbf + off) = hb;
}

// ---------------------------------------------------------------------------
// Head finish: hid[b][n] = relu(sum_kq P[kq][b][n] + bc1[n]). N=2048.
// ---------------------------------------------------------------------------
__global__ void headfin_kernel(const float* __restrict__ P, int nkq,
                               const float* __restrict__ bc1, float* __restrict__ hid)
{
    const int idx = blockIdx.x * blockDim.x + threadIdx.x;  // 0..32767
    const int b = idx >> 9;
    const int n = (idx & 511) * 4;
    f32x4 s = {0.f, 0.f, 0.f, 0.f};
    for (int kq = 0; kq < nkq; ++kq)
        s += *(const f32x4*)(P + ((long)kq * 64 + b) * 2048 + n);
    s += *(const f32x4*)(bc1 + n);
    #pragma unroll
    for (int e = 0; e < 4; ++e) s[e] = fmaxf(s[e], 0.f);
    *(f32x4*)(hid + (long)b * 2048 + n) = s;
}

// ---------------------------------------------------------------------------
// count = relu(hid @ Wc2^T + bc2). [64,2048] x [2048] -> [64].
// ---------------------------------------------------------------------------
__global__ void count_kernel(const float* __restrict__ hid, const float* __restrict__ Wc2,
                             const float* __restrict__ bc2, float* __restrict__ out)
{
    const int tid = threadIdx.x;
    const int b = tid >> 2, q = tid & 3;
    const float* hp = hid + (long)b * 2048 + q * 512;
    const float* wp = Wc2 + q * 512;
    float s = 0.f;
    #pragma unroll 4
    for (int k = 0; k < 512; k += 4) {
        f32x4 h4 = *(const f32x4*)(hp + k);
        f32x4 w4 = *(const f32x4*)(wp + k);
        s += h4[0] * w4[0] + h4[1] * w4[1] + h4[2] * w4[2] + h4[3] * w4[3];
    }
    s += __shfl_xor(s, 1);
    s += __shfl_xor(s, 2);
    if (q == 0) out[b] = fmaxf(s + bc2[0], 0.f);
}

// ---------------------------------------------------------------------------
extern "C" void kernel_launch(void* const* d_in, const int* in_sizes, int n_in,
                              void* d_out, int out_size, void* d_ws, size_t ws_size,
                              hipStream_t stream)
{
    const float* X    = (const float*)d_in[0];
    const float* h0   = (const float*)d_in[1];
    const float* c0   = (const float*)d_in[2];
    const float* Wih0 = (const float*)d_in[3];
    const float* Whh0 = (const float*)d_in[4];
    const float* bih0 = (const float*)d_in[5];
    const float* bhh0 = (const float*)d_in[6];
    const float* Wih1 = (const float*)d_in[7];
    const float* Whh1 = (const float*)d_in[8];
    const float* bih1 = (const float*)d_in[9];
    const float* bhh1 = (const float*)d_in[10];
    const float* Wc1  = (const float*)d_in[11];
    const float* bc1  = (const float*)d_in[12];
    const float* Wc2  = (const float*)d_in[13];
    const float* bc2  = (const float*)d_in[14];

    float* out  = (float*)d_out;
    float* ms   = out;                  // memory_state [64][4096]
    float* hnew = out + 262144;         // h_new [2][64][4096]
    float* cnew = out + 786432;         // c_new [2][64][4096]
    float* cnt  = out + 1310720;        // count [64]

    char* ws = (char*)d_ws;
    short* Xbf  = (short*)ws;                       // 512 KB
    short* H0bf = (short*)(ws + (1u << 19));        // 1 MB
    short* h1bf = (short*)(ws + 3u * (1u << 19));   // 512 KB
    short* h2bf = (short*)(ws + (1u << 21));        // 512 KB
    float* hid  = (float*)(ws + 5u * (1u << 19));   // 512 KB
    float* Pp   = (float*)(ws + 3u * (1u << 20));   // 16 MB partials (nkq=4)

    // nkq=4, KB=2048: the measured-best r2 config (occupancy counter proved
    // r2 ran this branch: 4 blocks/CU, 16 waves/CU, 186 us/layer).
    const int nkq = 4;
    const int KBl = 2048;

    hipLaunchKernelGGL(convert_kernel, dim3(768), dim3(256), 0, stream, X, h0, Xbf, H0bf);

    hipLaunchKernelGGL(gemm_part_kernel, dim3(256 * nkq), dim3(256), 0, stream,
                       Xbf, H0bf, Wih0, Whh0, Pp, 16384, nkq, KBl);
    hipLaunchKernelGGL(cell_kernel, dim3(256), dim3(256), 0, stream,
                       Pp, nkq, bih0, bhh0, c0, hnew, cnew, (float*)nullptr, h1bf);

    hipLaunchKernelGGL(gemm_part_kernel, dim3(256 * nkq), dim3(256), 0, stream,
                       h1bf, H0bf + 262144, Wih1, Whh1, Pp, 16384, nkq, KBl);
    hipLaunchKernelGGL(cell_kernel, dim3(256), dim3(256), 0, stream,
                       Pp, nkq, bih1, bhh1, c0 + 262144, hnew + 262144, cnew + 262144, ms, h2bf);

    // head: N=2048, K=4096 -> halves of 2048, nkq=8, KB=512, grid 256
    hipLaunchKernelGGL(gemm_part_kernel, dim3(32 * 8), dim3(256), 0, stream,
                       h2bf, h2bf + 2048, Wc1, Wc1 + 2048, Pp, 2048, 8, 512);
    hipLaunchKernelGGL(headfin_kernel, dim3(128), dim3(256), 0, stream, Pp, 8, bc1, hid);
    hipLaunchKernelGGL(count_kernel, dim3(1), dim3(256), 0, stream, hid, Wc2, bc2, cnt);
}